// Round 11
// baseline (1172.980 us; speedup 1.0000x reference)
//
#include <hip/hip_runtime.h>
#include <math.h>

#define NT 4096      // B*S tokens
#define Dm 2048
#define Hm 4096
#define NEx 8
#define CAPROWS 9216 // 8192 assignments + up to 8*127 padding, rounded

typedef float f32x4 __attribute__((ext_vector_type(4)));
typedef _Float16 f16x8 __attribute__((ext_vector_type(8)));

// ---------------- init ----------------
__global__ void k_init(int* meta) {
    if (threadIdx.x < NEx) meta[threadIdx.x] = 0;
}

// ---------------- persistent conv worker: f32 [e][K][N] -> f16 [e][N][K] ----------------
// Grid-strides over 64x64 tiles with register double-buffer (prefetch next tile's loads
// while transposing/storing the current one). Non-temporal on both sides (pure stream).
__device__ void conv_worker(const float* __restrict__ src, _Float16* __restrict__ dst,
                            int K, int N, int total, int wid, int nw,
                            float (*tile)[65]) {
    const int tx = threadIdx.x & 15, ty = threadIdx.x >> 4;
    const int nx = N >> 6, nk = K >> 6;
    int t = wid;
    if (t >= total) return;

    auto loadt = [&](int tt, f32x4* vv) {
        int nb = tt % nx; int kb = (tt / nx) % nk; int e = tt / (nx * nk);
        const float* S = src + (size_t)e * K * N + (size_t)(kb * 64) * N + nb * 64;
#pragma unroll
        for (int p = 0; p < 4; ++p)
            vv[p] = __builtin_nontemporal_load(
                (const f32x4*)(S + (size_t)(p * 16 + ty) * N + tx * 4));
    };

    f32x4 v[4];
    loadt(t, v);
    for (;;) {
#pragma unroll
        for (int p = 0; p < 4; ++p) {
            int kr = p * 16 + ty;
            tile[kr][tx * 4 + 0] = v[p][0]; tile[kr][tx * 4 + 1] = v[p][1];
            tile[kr][tx * 4 + 2] = v[p][2]; tile[kr][tx * 4 + 3] = v[p][3];
        }
        __syncthreads();
        const int tn = t + nw;
        f32x4 v2[4];
        if (tn < total) loadt(tn, v2);          // prefetch: overlaps LDS transpose + store
        const int n = threadIdx.x >> 2, seg = threadIdx.x & 3;
        f16x8 o0, o1;
#pragma unroll
        for (int j = 0; j < 8; ++j) o0[j] = (_Float16)tile[seg * 16 + j][n];
#pragma unroll
        for (int j = 0; j < 8; ++j) o1[j] = (_Float16)tile[seg * 16 + 8 + j][n];
        {
            int nb = t % nx; int kb = (t / nx) % nk; int e = t / (nx * nk);
            _Float16* dp = dst + (size_t)e * K * N + (size_t)(nb * 64 + n) * K + kb * 64 + seg * 16;
            __builtin_nontemporal_store(o0, (f16x8*)dp);
            __builtin_nontemporal_store(o1, (f16x8*)(dp + 8));
        }
        if (tn >= total) return;
        __syncthreads();                         // all LDS reads done before next store
#pragma unroll
        for (int p = 0; p < 4; ++p) v[p] = v2[p];
        t = tn;
    }
}

// standalone conv (serial fallback path): persistent workers
__global__ __launch_bounds__(256, 2) void k_convw(const float* __restrict__ src,
                                                  _Float16* __restrict__ dst, int K, int N,
                                                  int total) {
    __shared__ float tile[64][65];
    conv_worker(src, dst, K, N, total, blockIdx.x, gridDim.x, tile);
}

// ---------------- gate (4 tokens/block, 1 wave each) + conv workers tail-appended ----------------
__global__ __launch_bounds__(256, 2)
void k_gateconv(const float* __restrict__ x, const float* __restrict__ Wg,
                const float* __restrict__ bg, int* __restrict__ meta,
                int* __restrict__ list, float* __restrict__ topw,
                const float* __restrict__ csrc, _Float16* __restrict__ cdst,
                int cK, int cN, int cTotal) {
    __shared__ float tile[64][65];
    const int bid = blockIdx.x;
    if (bid >= NT / 4) {
        conv_worker(csrc, cdst, cK, cN, cTotal, bid - NT / 4, gridDim.x - NT / 4, tile);
        return;
    }
    int lane = threadIdx.x & 63;
    int t = bid * 4 + (threadIdx.x >> 6);
    const float* xr = x + (size_t)t * Dm;
    double acc[NEx];
#pragma unroll
    for (int j = 0; j < NEx; ++j) acc[j] = 0.0;
    for (int d = lane; d < Dm; d += 64) {
        double xv = (double)xr[d];
        const float* wr = Wg + (size_t)d * NEx;
#pragma unroll
        for (int j = 0; j < NEx; ++j) acc[j] += xv * (double)wr[j];
    }
#pragma unroll
    for (int off = 32; off > 0; off >>= 1) {
#pragma unroll
        for (int j = 0; j < NEx; ++j) acc[j] += __shfl_xor(acc[j], off, 64);
    }
    if (lane == 0) {
        double l[NEx];
#pragma unroll
        for (int j = 0; j < NEx; ++j) l[j] = acc[j] + (double)bg[j];
        double m = l[0];
        for (int j = 1; j < NEx; ++j) m = l[j] > m ? l[j] : m;
        double s = 0.0, ev[NEx];
        for (int j = 0; j < NEx; ++j) { ev[j] = exp(l[j] - m); s += ev[j]; }
        int i0 = 0; double v0 = l[0];
        for (int j = 1; j < NEx; ++j) if (l[j] > v0) { v0 = l[j]; i0 = j; }
        int i1 = -1; double v1 = -1e300;
        for (int j = 0; j < NEx; ++j) if (j != i0 && l[j] > v1) { v1 = l[j]; i1 = j; }
        topw[2 * t]     = (float)(ev[i0] / s);
        topw[2 * t + 1] = (float)(ev[i1] / s);
        int p0 = atomicAdd(&meta[i0], 1); list[i0 * NT + p0] = 2 * t;
        int p1 = atomicAdd(&meta[i1], 1); list[i1 * NT + p1] = 2 * t + 1;
    }
}

// ---------------- plan: padded counts + prefix offsets (pad to 128) ----------------
__global__ void k_plan(int* meta) {
    if (threadIdx.x == 0 && blockIdx.x == 0) {
        int tot = 0;
        for (int e = 0; e < NEx; ++e) {
            int c = meta[e];
            meta[8 + e] = c;                 // counts
            int cp = (c + 127) & ~127;       // padded to 128 (BM)
            meta[16 + e] = cp;               // cps
            meta[24 + e] = tot;              // offs
            tot += cp;
        }
        meta[32] = tot;                      // total padded rows
    }
}

// ---------------- gather: x rows -> fp16 compact buffer, zero padding ----------------
__global__ void k_gather(const float* __restrict__ x, const int* __restrict__ meta,
                         const int* __restrict__ list, int* __restrict__ pos_of,
                         _Float16* __restrict__ Xg) {
    int r = blockIdx.x;
    if (r >= meta[32]) return;
    int e = 0;
    while (r >= meta[24 + e + 1]) ++e;
    int i = r - meta[24 + e];
    _Float16* dst = Xg + (size_t)r * Dm + threadIdx.x * 8;
    if (i < meta[8 + e]) {
        int v = list[e * NT + i];
        int t = v >> 1;
        if (threadIdx.x == 0) pos_of[v] = r;
        const float* src = x + (size_t)t * Dm + threadIdx.x * 8;
        f32x4 a = *(const f32x4*)(src);
        f32x4 b = *(const f32x4*)(src + 4);
        f16x8 o;
        o[0] = (_Float16)a[0]; o[1] = (_Float16)a[1]; o[2] = (_Float16)a[2]; o[3] = (_Float16)a[3];
        o[4] = (_Float16)b[0]; o[5] = (_Float16)b[1]; o[6] = (_Float16)b[2]; o[7] = (_Float16)b[3];
        *(f16x8*)dst = o;
    } else {
        f16x8 z = (f16x8)(_Float16)0.0f;
        *(f16x8*)dst = z;
    }
}

// ---------------- GEMM: 128x128 tile, BK=64, 16x16x32 MFMA; conv workers tail-appended ----------------
__device__ __forceinline__ void gload16(const void* g, void* l) {
    __builtin_amdgcn_global_load_lds((__attribute__((address_space(1))) void*)(g),
                                     (__attribute__((address_space(3))) void*)(l),
                                     16, 0, 0);
}

__device__ __forceinline__ float gelu_f(float v) {
    return 0.5f * v * (1.0f + erff(v * 0.70710678118654752f));
}

template <int KDIM, int NDIM, bool GELU>
__global__ __launch_bounds__(256, 4)
void k_gemmconv(const _Float16* __restrict__ Abase, const _Float16* __restrict__ Wt,
                const float* __restrict__ bias, void* __restrict__ Cout,
                const int* __restrict__ meta,
                const float* __restrict__ csrc, _Float16* __restrict__ cdst,
                int cK, int cN, int cTotal,
                int nGemm) {
    __shared__ char smem[32768];   // gemm: ldsA 16K | ldsB 16K ; conv: 16640 of it
    const int bid = blockIdx.x;
    if (bid >= nGemm) {
        conv_worker(csrc, cdst, cK, cN, cTotal, bid - nGemm, gridDim.x - nGemm,
                    (float(*)[65])smem);
        return;
    }

    constexpr int GX = NDIM / 128;
    constexpr int GY = 32;
    constexpr int NBLK = GX * GY;        // divisible by 8
    const int e = bid / NBLK;
    const int f = bid % NBLK;
    // XCD-chunked bijective remap (same-nt blocks adjacent per XCD)
    const int fp = (f & 7) * (NBLK >> 3) + (f >> 3);
    const int nt = fp / GY;
    const int mt = fp % GY;
    const int cp = meta[16 + e];
    if (mt * 128 >= cp) return;
    const int row0 = meta[24 + e] + mt * 128;

    _Float16* ldsA = (_Float16*)smem;
    _Float16* ldsB = (_Float16*)(smem + 16384);

    const int tid = threadIdx.x;
    const int lane = tid & 63;
    const int wv = tid >> 6;
    const int wm = wv >> 1, wn = wv & 1;

    const char* Ag = (const char*)(Abase + (size_t)row0 * KDIM);
    const char* Bg = (const char*)(Wt + ((size_t)e * NDIM + (size_t)nt * 128) * KDIM);

    // staging: linear LDS dest, pre-swizzled global source (swizzle = (row&7)<<4 on byte col)
    int soff[4];
#pragma unroll
    for (int r = 0; r < 4; ++r) {
        int L = r * 4096 + tid * 16;
        int row = L >> 7;        // 128 B per row (64 f16)
        int col = L & 127;
        int scol = col ^ ((row & 7) << 4);
        soff[r] = row * (KDIM * 2) + scol;
    }

    f32x4 acc[4][4];
#pragma unroll
    for (int i = 0; i < 4; ++i)
#pragma unroll
        for (int j = 0; j < 4; ++j)
            acc[i][j] = (f32x4){0.f, 0.f, 0.f, 0.f};

    int abase[4], aswz[4], bbase[4], bswz[4];
#pragma unroll
    for (int m = 0; m < 4; ++m) {
        int rA = wm * 64 + m * 16 + (lane & 15);
        abase[m] = rA * 128;
        aswz[m] = (rA & 7) << 4;
    }
#pragma unroll
    for (int n = 0; n < 4; ++n) {
        int rB = wn * 64 + n * 16 + (lane & 15);
        bbase[n] = rB * 128;
        bswz[n] = (rB & 7) << 4;
    }
    const int hib = (lane >> 4) * 16;

    const char* cldsA = (const char*)ldsA;
    const char* cldsB = (const char*)ldsB;

    for (int kt = 0; kt < KDIM / 64; ++kt) {
        const int kbyte = kt * 128;
#pragma unroll
        for (int r = 0; r < 4; ++r) {
            gload16(Ag + (soff[r] + kbyte), (char*)ldsA + r * 4096 + tid * 16);
            gload16(Bg + (soff[r] + kbyte), (char*)ldsB + r * 4096 + tid * 16);
        }
        __syncthreads();
#pragma unroll
        for (int ks = 0; ks < 2; ++ks) {
            const int cbs = ks * 64 + hib;
            f16x8 av[4], bv[4];
#pragma unroll
            for (int m = 0; m < 4; ++m)
                av[m] = *(const f16x8*)(cldsA + abase[m] + (cbs ^ aswz[m]));
#pragma unroll
            for (int n = 0; n < 4; ++n)
                bv[n] = *(const f16x8*)(cldsB + bbase[n] + (cbs ^ bswz[n]));
#pragma unroll
            for (int m = 0; m < 4; ++m)
#pragma unroll
                for (int n = 0; n < 4; ++n)
                    acc[m][n] = __builtin_amdgcn_mfma_f32_16x16x32_f16(av[m], bv[n], acc[m][n], 0, 0, 0);
        }
        __syncthreads();
    }

    // epilogue: C/D frag mapping col=lane&15, row=(lane>>4)*4+reg
    const int lcol = lane & 15;
    const int rowq = (lane >> 4) * 4;
#pragma unroll
    for (int m = 0; m < 4; ++m) {
#pragma unroll
        for (int n = 0; n < 4; ++n) {
            const int gcol = nt * 128 + wn * 64 + n * 16 + lcol;
            const float bb = bias[(size_t)e * NDIM + gcol];
#pragma unroll
            for (int v = 0; v < 4; ++v) {
                const int grow = row0 + wm * 64 + m * 16 + rowq + v;
                float val = acc[m][n][v] + bb;
                if constexpr (GELU) {
                    ((_Float16*)Cout)[(size_t)grow * NDIM + gcol] = (_Float16)gelu_f(val);
                } else {
                    ((float*)Cout)[(size_t)grow * NDIM + gcol] = val;
                }
            }
        }
    }
}

// ---------------- combine: out[t] = w0*eo[r0] + w1*eo[r1] ----------------
__global__ void k_combine(const float* __restrict__ eo, const int* __restrict__ pos_of,
                          const float* __restrict__ topw, float* __restrict__ out) {
    int t = blockIdx.x;
    int r0 = pos_of[2 * t], r1 = pos_of[2 * t + 1];
    float w0 = topw[2 * t], w1 = topw[2 * t + 1];
    const f32x4* e0 = (const f32x4*)(eo + (size_t)r0 * Dm);
    const f32x4* e1 = (const f32x4*)(eo + (size_t)r1 * Dm);
    f32x4* op = (f32x4*)(out + (size_t)t * Dm);
    for (int i = threadIdx.x; i < Dm / 4; i += 256) {
        f32x4 a = e0[i], b = e1[i];
        op[i] = a * w0 + b * w1;
    }
}

extern "C" void kernel_launch(void* const* d_in, const int* in_sizes, int n_in,
                              void* d_out, int out_size, void* d_ws, size_t ws_size,
                              hipStream_t stream) {
    const float* x  = (const float*)d_in[0];
    const float* W1 = (const float*)d_in[1];
    const float* b1 = (const float*)d_in[2];
    const float* W2 = (const float*)d_in[3];
    const float* b2 = (const float*)d_in[4];
    const float* W3 = (const float*)d_in[5];
    const float* b3 = (const float*)d_in[6];
    const float* Wg = (const float*)d_in[7];
    const float* bg = (const float*)d_in[8];
    float* out = (float*)d_out;
    (void)in_sizes; (void)n_in; (void)out_size;

    char* ws = (char*)d_ws;
    int*   meta   = (int*)ws;                                // 64 ints
    int*   list   = (int*)(ws + 256);                        // 8*4096 ints
    int*   pos_of = (int*)(ws + 256 + 131072);               // 8192 ints
    float* topw   = (float*)(ws + 256 + 131072 + 32768);     // 8192 f32
    size_t off = 196864;                                     // 256-aligned

    // conv tile counts + persistent worker counts
    const int nC1 = (Hm / 64) * (Dm / 64) * NEx;   // 16384
    const int nC2 = (Hm / 64) * (Hm / 64) * NEx;   // 32768
    const int nC3 = (Dm / 64) * (Hm / 64) * NEx;   // 16384
    const int CW1 = 2048, CW2 = 2048, CW3 = 1024;
    const int nG12 = NEx * (Hm / 128) * 32;        // 8192
    const int nG3  = NEx * (Dm / 128) * 32;        // 4096

    const size_t sXg  = (size_t)CAPROWS * Dm * 2;   // 37.7 MB
    const size_t sWb1 = (size_t)NEx * Dm * Hm * 2;  // 134.2 MB
    const size_t sWb2 = (size_t)NEx * Hm * Hm * 2;  // 268.4 MB
    const size_t sWb3 = (size_t)NEx * Hm * Dm * 2;  // 134.2 MB
    const size_t sH   = (size_t)CAPROWS * Hm * 2;   // 75.5 MB

    const size_t needPar = off + sXg + sWb1 + sWb2 + sWb3 + sH + sH;  // ~726 MB

    if (ws_size >= needPar) {
        // ----- parallel layout: conv1 under gate, conv2 under GEMM1, conv3 under GEMM2 -----
        _Float16* Xg  = (_Float16*)(ws + off); off += sXg;
        _Float16* Wb1 = (_Float16*)(ws + off); off += sWb1;
        _Float16* Wb2 = (_Float16*)(ws + off); off += sWb2;
        _Float16* Wb3 = (_Float16*)(ws + off); off += sWb3;
        _Float16* h1  = (_Float16*)(ws + off); off += sH;
        _Float16* h2  = (_Float16*)(ws + off); off += sH;
        float*    eo  = (float*)Wb1;           // Wb1 dead after GEMM1; eo (75.5MB) fits

        k_init<<<1, 64, 0, stream>>>(meta);
        k_gateconv<<<NT / 4 + CW1, 256, 0, stream>>>(x, Wg, bg, meta, list, topw,
                                                     W1, Wb1, Dm, Hm, nC1);
        k_plan<<<1, 1, 0, stream>>>(meta);
        k_gather<<<CAPROWS, 256, 0, stream>>>(x, meta, list, pos_of, Xg);

        k_gemmconv<Dm, Hm, true><<<nG12 + CW2, 256, 0, stream>>>(
            Xg, Wb1, b1, (void*)h1, meta, W2, Wb2, Hm, Hm, nC2, nG12);
        k_gemmconv<Hm, Hm, true><<<nG12 + CW3, 256, 0, stream>>>(
            h1, Wb2, b2, (void*)h2, meta, W3, Wb3, Hm, Dm, nC3, nG12);
        k_gemmconv<Hm, Dm, false><<<nG3, 256, 0, stream>>>(
            h2, Wb3, b3, (void*)eo, meta,
            (const float*)0, (_Float16*)0, 0, 0, 0, nG3);

        k_combine<<<NT, 256, 0, stream>>>(eo, pos_of, topw, out);
    } else {
        // ----- serial fallback (shared weight buffer) -----
        _Float16* Xg = (_Float16*)(ws + off); off += sXg;
        _Float16* Wb = (_Float16*)(ws + off); off += sWb2;
        _Float16* h2 = (_Float16*)(ws + off); off += sH;
        _Float16* h1 = (_Float16*)(ws + off);
        float*    eo = (float*)(ws + off);

        k_init<<<1, 64, 0, stream>>>(meta);
        k_gateconv<<<NT / 4, 256, 0, stream>>>(x, Wg, bg, meta, list, topw,
                                               (const float*)0, (_Float16*)0, 0, 0, 0);
        k_plan<<<1, 1, 0, stream>>>(meta);
        k_gather<<<CAPROWS, 256, 0, stream>>>(x, meta, list, pos_of, Xg);

        k_convw<<<CW1, 256, 0, stream>>>(W1, Wb, Dm, Hm, nC1);
        k_gemmconv<Dm, Hm, true><<<nG12, 256, 0, stream>>>(
            Xg, Wb, b1, (void*)h1, meta,
            (const float*)0, (_Float16*)0, 0, 0, 0, nG12);

        k_convw<<<CW2, 256, 0, stream>>>(W2, Wb, Hm, Hm, nC2);
        k_gemmconv<Hm, Hm, true><<<nG12, 256, 0, stream>>>(
            h1, Wb, b2, (void*)h2, meta,
            (const float*)0, (_Float16*)0, 0, 0, 0, nG12);

        k_convw<<<CW3, 256, 0, stream>>>(W3, Wb, Hm, Dm, nC3);
        k_gemmconv<Hm, Dm, false><<<nG3, 256, 0, stream>>>(
            h2, Wb, b3, (void*)eo, meta,
            (const float*)0, (_Float16*)0, 0, 0, 0, nG3);

        k_combine<<<NT, 256, 0, stream>>>(eo, pos_of, topw, out);
    }
}

// Round 12
// 1093.108 us; speedup vs baseline: 1.0731x; 1.0731x over previous
//
#include <hip/hip_runtime.h>
#include <math.h>

#define NT 4096      // B*S tokens
#define Dm 2048
#define Hm 4096
#define NEx 8
#define CAPROWS 9216 // 8192 assignments + up to 8*127 padding, rounded

typedef float f32x4 __attribute__((ext_vector_type(4)));
typedef _Float16 f16x8 __attribute__((ext_vector_type(8)));

// ---------------- init ----------------
__global__ void k_init(int* meta) {
    if (threadIdx.x < NEx) meta[threadIdx.x] = 0;
}

// ---------------- conv tile: f32 [e][K][N] -> f16 [e][N][K], 64x64 tile, non-temporal ----------------
__device__ __forceinline__ void conv_tile(const float* __restrict__ src, _Float16* __restrict__ dst,
                                          int K, int N, int t, float (*tile)[65]) {
    int nx = N >> 6, nk = K >> 6;
    int nb = t % nx;
    int kb = (t / nx) % nk;
    int e  = t / (nx * nk);
    int n0 = nb * 64, k0 = kb * 64;
    size_t ebase = (size_t)e * (size_t)K * (size_t)N;
    const float* S = src + ebase;
    _Float16* Dd = dst + ebase;
    int tx = threadIdx.x & 15, ty = threadIdx.x >> 4;
#pragma unroll
    for (int p = 0; p < 4; ++p) {
        int kr = p * 16 + ty;
        f32x4 v = __builtin_nontemporal_load((const f32x4*)(S + (size_t)(k0 + kr) * N + n0 + tx * 4));
        tile[kr][tx * 4 + 0] = v[0]; tile[kr][tx * 4 + 1] = v[1];
        tile[kr][tx * 4 + 2] = v[2]; tile[kr][tx * 4 + 3] = v[3];
    }
    __syncthreads();
    int n = threadIdx.x >> 2, seg = threadIdx.x & 3;
    f16x8 o0, o1;
#pragma unroll
    for (int j = 0; j < 8; ++j) o0[j] = (_Float16)tile[seg * 16 + j][n];
#pragma unroll
    for (int j = 0; j < 8; ++j) o1[j] = (_Float16)tile[seg * 16 + 8 + j][n];
    _Float16* dp = Dd + (size_t)(n0 + n) * K + k0 + seg * 16;
    __builtin_nontemporal_store(o0, (f16x8*)dp);
    __builtin_nontemporal_store(o1, (f16x8*)(dp + 8));
}

// standalone conv (serial fallback path): one tile per block
__global__ __launch_bounds__(256, 2) void k_convw(const float* __restrict__ src,
                                                  _Float16* __restrict__ dst, int K, int N) {
    __shared__ float tile[64][65];
    conv_tile(src, dst, K, N, blockIdx.x, tile);
}

// ---------------- gate (4 tokens/block, 1 wave each) + TWO conv jobs tail-appended ----------------
__global__ __launch_bounds__(256, 2)
void k_gateconv(const float* __restrict__ x, const float* __restrict__ Wg,
                const float* __restrict__ bg, int* __restrict__ meta,
                int* __restrict__ list, float* __restrict__ topw,
                const float* __restrict__ c1src, _Float16* __restrict__ c1dst, int c1K, int c1N, int n1,
                const float* __restrict__ c2src, _Float16* __restrict__ c2dst, int c2K, int c2N) {
    __shared__ float tile[64][65];
    const int bid = blockIdx.x;
    if (bid >= NT / 4) {
        const int t = bid - NT / 4;
        if (t < n1) conv_tile(c1src, c1dst, c1K, c1N, t, tile);
        else        conv_tile(c2src, c2dst, c2K, c2N, t - n1, tile);
        return;
    }
    int lane = threadIdx.x & 63;
    int t = bid * 4 + (threadIdx.x >> 6);
    const float* xr = x + (size_t)t * Dm;
    double acc[NEx];
#pragma unroll
    for (int j = 0; j < NEx; ++j) acc[j] = 0.0;
    for (int d = lane; d < Dm; d += 64) {
        double xv = (double)xr[d];
        const float* wr = Wg + (size_t)d * NEx;
#pragma unroll
        for (int j = 0; j < NEx; ++j) acc[j] += xv * (double)wr[j];
    }
#pragma unroll
    for (int off = 32; off > 0; off >>= 1) {
#pragma unroll
        for (int j = 0; j < NEx; ++j) acc[j] += __shfl_xor(acc[j], off, 64);
    }
    if (lane == 0) {
        double l[NEx];
#pragma unroll
        for (int j = 0; j < NEx; ++j) l[j] = acc[j] + (double)bg[j];
        double m = l[0];
        for (int j = 1; j < NEx; ++j) m = l[j] > m ? l[j] : m;
        double s = 0.0, ev[NEx];
        for (int j = 0; j < NEx; ++j) { ev[j] = exp(l[j] - m); s += ev[j]; }
        int i0 = 0; double v0 = l[0];
        for (int j = 1; j < NEx; ++j) if (l[j] > v0) { v0 = l[j]; i0 = j; }
        int i1 = -1; double v1 = -1e300;
        for (int j = 0; j < NEx; ++j) if (j != i0 && l[j] > v1) { v1 = l[j]; i1 = j; }
        topw[2 * t]     = (float)(ev[i0] / s);
        topw[2 * t + 1] = (float)(ev[i1] / s);
        int p0 = atomicAdd(&meta[i0], 1); list[i0 * NT + p0] = 2 * t;
        int p1 = atomicAdd(&meta[i1], 1); list[i1 * NT + p1] = 2 * t + 1;
    }
}

// ---------------- plan: padded counts + prefix offsets (pad to 128) ----------------
__global__ void k_plan(int* meta) {
    if (threadIdx.x == 0 && blockIdx.x == 0) {
        int tot = 0;
        for (int e = 0; e < NEx; ++e) {
            int c = meta[e];
            meta[8 + e] = c;                 // counts
            int cp = (c + 127) & ~127;       // padded to 128 (BM)
            meta[16 + e] = cp;               // cps
            meta[24 + e] = tot;              // offs
            tot += cp;
        }
        meta[32] = tot;                      // total padded rows
    }
}

// ---------------- gather: x rows -> fp16 compact buffer + ONE conv job tail-appended ----------------
__global__ void k_gather(const float* __restrict__ x, const int* __restrict__ meta,
                         const int* __restrict__ list, int* __restrict__ pos_of,
                         _Float16* __restrict__ Xg,
                         const float* __restrict__ csrc, _Float16* __restrict__ cdst,
                         int cK, int cN, int cBase) {
    int r = blockIdx.x;
    if (r >= CAPROWS) {
        __shared__ float tile[64][65];
        conv_tile(csrc, cdst, cK, cN, cBase + (r - CAPROWS), tile);
        return;
    }
    if (r >= meta[32]) return;
    int e = 0;
    while (r >= meta[24 + e + 1]) ++e;
    int i = r - meta[24 + e];
    _Float16* dst = Xg + (size_t)r * Dm + threadIdx.x * 8;
    if (i < meta[8 + e]) {
        int v = list[e * NT + i];
        int t = v >> 1;
        if (threadIdx.x == 0) pos_of[v] = r;
        const float* src = x + (size_t)t * Dm + threadIdx.x * 8;
        f32x4 a = *(const f32x4*)(src);
        f32x4 b = *(const f32x4*)(src + 4);
        f16x8 o;
        o[0] = (_Float16)a[0]; o[1] = (_Float16)a[1]; o[2] = (_Float16)a[2]; o[3] = (_Float16)a[3];
        o[4] = (_Float16)b[0]; o[5] = (_Float16)b[1]; o[6] = (_Float16)b[2]; o[7] = (_Float16)b[3];
        *(f16x8*)dst = o;
    } else {
        f16x8 z = (f16x8)(_Float16)0.0f;
        *(f16x8*)dst = z;
    }
}

// ---------------- GEMM: 128x128 tile, BK=64, 16x16x32 MFMA; ONE conv job tail-appended ----------------
__device__ __forceinline__ void gload16(const void* g, void* l) {
    __builtin_amdgcn_global_load_lds((__attribute__((address_space(1))) void*)(g),
                                     (__attribute__((address_space(3))) void*)(l),
                                     16, 0, 0);
}

__device__ __forceinline__ float gelu_f(float v) {
    return 0.5f * v * (1.0f + erff(v * 0.70710678118654752f));
}

template <int KDIM, int NDIM, bool GELU>
__global__ __launch_bounds__(256, 4)
void k_gemmconv(const _Float16* __restrict__ Abase, const _Float16* __restrict__ Wt,
                const float* __restrict__ bias, void* __restrict__ Cout,
                const int* __restrict__ meta,
                const float* __restrict__ csrc, _Float16* __restrict__ cdst,
                int cK, int cN, int cBase,
                int nGemm) {
    __shared__ char smem[32768];   // gemm: ldsA 16K | ldsB 16K ; conv: 16640 of it
    const int bid = blockIdx.x;
    if (bid >= nGemm) {
        conv_tile(csrc, cdst, cK, cN, cBase + (bid - nGemm), (float(*)[65])smem);
        return;
    }

    constexpr int GX = NDIM / 128;
    constexpr int GY = 32;
    constexpr int NBLK = GX * GY;        // divisible by 8
    const int e = bid / NBLK;
    const int f = bid % NBLK;
    // XCD-chunked bijective remap (same-nt blocks adjacent per XCD)
    const int fp = (f & 7) * (NBLK >> 3) + (f >> 3);
    const int nt = fp / GY;
    const int mt = fp % GY;
    const int cp = meta[16 + e];
    if (mt * 128 >= cp) return;
    const int row0 = meta[24 + e] + mt * 128;

    _Float16* ldsA = (_Float16*)smem;
    _Float16* ldsB = (_Float16*)(smem + 16384);

    const int tid = threadIdx.x;
    const int lane = tid & 63;
    const int wv = tid >> 6;
    const int wm = wv >> 1, wn = wv & 1;

    const char* Ag = (const char*)(Abase + (size_t)row0 * KDIM);
    const char* Bg = (const char*)(Wt + ((size_t)e * NDIM + (size_t)nt * 128) * KDIM);

    // staging: linear LDS dest, pre-swizzled global source (swizzle = (row&7)<<4 on byte col)
    int soff[4];
#pragma unroll
    for (int r = 0; r < 4; ++r) {
        int L = r * 4096 + tid * 16;
        int row = L >> 7;        // 128 B per row (64 f16)
        int col = L & 127;
        int scol = col ^ ((row & 7) << 4);
        soff[r] = row * (KDIM * 2) + scol;
    }

    f32x4 acc[4][4];
#pragma unroll
    for (int i = 0; i < 4; ++i)
#pragma unroll
        for (int j = 0; j < 4; ++j)
            acc[i][j] = (f32x4){0.f, 0.f, 0.f, 0.f};

    int abase[4], aswz[4], bbase[4], bswz[4];
#pragma unroll
    for (int m = 0; m < 4; ++m) {
        int rA = wm * 64 + m * 16 + (lane & 15);
        abase[m] = rA * 128;
        aswz[m] = (rA & 7) << 4;
    }
#pragma unroll
    for (int n = 0; n < 4; ++n) {
        int rB = wn * 64 + n * 16 + (lane & 15);
        bbase[n] = rB * 128;
        bswz[n] = (rB & 7) << 4;
    }
    const int hib = (lane >> 4) * 16;

    const char* cldsA = (const char*)ldsA;
    const char* cldsB = (const char*)ldsB;

    for (int kt = 0; kt < KDIM / 64; ++kt) {
        const int kbyte = kt * 128;
#pragma unroll
        for (int r = 0; r < 4; ++r) {
            gload16(Ag + (soff[r] + kbyte), (char*)ldsA + r * 4096 + tid * 16);
            gload16(Bg + (soff[r] + kbyte), (char*)ldsB + r * 4096 + tid * 16);
        }
        __syncthreads();
#pragma unroll
        for (int ks = 0; ks < 2; ++ks) {
            const int cbs = ks * 64 + hib;
            f16x8 av[4], bv[4];
#pragma unroll
            for (int m = 0; m < 4; ++m)
                av[m] = *(const f16x8*)(cldsA + abase[m] + (cbs ^ aswz[m]));
#pragma unroll
            for (int n = 0; n < 4; ++n)
                bv[n] = *(const f16x8*)(cldsB + bbase[n] + (cbs ^ bswz[n]));
#pragma unroll
            for (int m = 0; m < 4; ++m)
#pragma unroll
                for (int n = 0; n < 4; ++n)
                    acc[m][n] = __builtin_amdgcn_mfma_f32_16x16x32_f16(av[m], bv[n], acc[m][n], 0, 0, 0);
        }
        __syncthreads();
    }

    // epilogue: C/D frag mapping col=lane&15, row=(lane>>4)*4+reg
    const int lcol = lane & 15;
    const int rowq = (lane >> 4) * 4;
#pragma unroll
    for (int m = 0; m < 4; ++m) {
#pragma unroll
        for (int n = 0; n < 4; ++n) {
            const int gcol = nt * 128 + wn * 64 + n * 16 + lcol;
            const float bb = bias[(size_t)e * NDIM + gcol];
#pragma unroll
            for (int v = 0; v < 4; ++v) {
                const int grow = row0 + wm * 64 + m * 16 + rowq + v;
                float val = acc[m][n][v] + bb;
                if constexpr (GELU) {
                    ((_Float16*)Cout)[(size_t)grow * NDIM + gcol] = (_Float16)gelu_f(val);
                } else {
                    ((float*)Cout)[(size_t)grow * NDIM + gcol] = val;
                }
            }
        }
    }
}

// ---------------- combine: out[t] = w0*eo[r0] + w1*eo[r1] ----------------
__global__ void k_combine(const float* __restrict__ eo, const int* __restrict__ pos_of,
                          const float* __restrict__ topw, float* __restrict__ out) {
    int t = blockIdx.x;
    int r0 = pos_of[2 * t], r1 = pos_of[2 * t + 1];
    float w0 = topw[2 * t], w1 = topw[2 * t + 1];
    const f32x4* e0 = (const f32x4*)(eo + (size_t)r0 * Dm);
    const f32x4* e1 = (const f32x4*)(eo + (size_t)r1 * Dm);
    f32x4* op = (f32x4*)(out + (size_t)t * Dm);
    for (int i = threadIdx.x; i < Dm / 4; i += 256) {
        f32x4 a = e0[i], b = e1[i];
        op[i] = a * w0 + b * w1;
    }
}

extern "C" void kernel_launch(void* const* d_in, const int* in_sizes, int n_in,
                              void* d_out, int out_size, void* d_ws, size_t ws_size,
                              hipStream_t stream) {
    const float* x  = (const float*)d_in[0];
    const float* W1 = (const float*)d_in[1];
    const float* b1 = (const float*)d_in[2];
    const float* W2 = (const float*)d_in[3];
    const float* b2 = (const float*)d_in[4];
    const float* W3 = (const float*)d_in[5];
    const float* b3 = (const float*)d_in[6];
    const float* Wg = (const float*)d_in[7];
    const float* bg = (const float*)d_in[8];
    float* out = (float*)d_out;
    (void)in_sizes; (void)n_in; (void)out_size;

    char* ws = (char*)d_ws;
    int*   meta   = (int*)ws;                                // 64 ints
    int*   list   = (int*)(ws + 256);                        // 8*4096 ints
    int*   pos_of = (int*)(ws + 256 + 131072);               // 8192 ints
    float* topw   = (float*)(ws + 256 + 131072 + 32768);     // 8192 f32
    size_t off = 196864;                                     // 256-aligned

    // conv tile counts
    const int nC1 = (Hm / 64) * (Dm / 64) * NEx;   // 16384
    const int nC2 = (Hm / 64) * (Hm / 64) * NEx;   // 32768
    const int nC3 = (Dm / 64) * (Hm / 64) * NEx;   // 16384
    // conv2 split across its dependence-feasible hosts (all precede GEMM2)
    const int C2A = 12288;                         // rides gate launch   (295 MB)
    const int C2B = 8192;                          // rides gather launch (197 MB)
    const int C2C = nC2 - C2A - C2B;               // rides GEMM1 tail    (295 MB)
    const int nG12 = NEx * (Hm / 128) * 32;        // 8192
    const int nG3  = NEx * (Dm / 128) * 32;        // 4096

    const size_t sXg  = (size_t)CAPROWS * Dm * 2;   // 37.7 MB
    const size_t sWb1 = (size_t)NEx * Dm * Hm * 2;  // 134.2 MB
    const size_t sWb2 = (size_t)NEx * Hm * Hm * 2;  // 268.4 MB
    const size_t sWb3 = (size_t)NEx * Hm * Dm * 2;  // 134.2 MB
    const size_t sH   = (size_t)CAPROWS * Hm * 2;   // 75.5 MB

    const size_t needPar = off + sXg + sWb1 + sWb2 + sWb3 + sH + sH;  // ~726 MB

    if (ws_size >= needPar) {
        // ----- parallel layout: conv1+conv2a under gate, conv2b under gather,
        //       conv2c under GEMM1, conv3 under GEMM2; GEMM3 clean -----
        _Float16* Xg  = (_Float16*)(ws + off); off += sXg;
        _Float16* Wb1 = (_Float16*)(ws + off); off += sWb1;
        _Float16* Wb2 = (_Float16*)(ws + off); off += sWb2;
        _Float16* Wb3 = (_Float16*)(ws + off); off += sWb3;
        _Float16* h1  = (_Float16*)(ws + off); off += sH;
        _Float16* h2  = (_Float16*)(ws + off); off += sH;
        float*    eo  = (float*)Wb1;           // Wb1 dead after GEMM1; eo (75.5MB) fits

        k_init<<<1, 64, 0, stream>>>(meta);
        k_gateconv<<<NT / 4 + nC1 + C2A, 256, 0, stream>>>(
            x, Wg, bg, meta, list, topw,
            W1, Wb1, Dm, Hm, nC1,          // job1: conv1 tiles [0, nC1)
            W2, Wb2, Hm, Hm);              // job2: conv2 tiles [0, C2A)
        k_plan<<<1, 1, 0, stream>>>(meta);
        k_gather<<<CAPROWS + C2B, 256, 0, stream>>>(
            x, meta, list, pos_of, Xg,
            W2, Wb2, Hm, Hm, C2A);         // conv2 tiles [C2A, C2A+C2B)

        k_gemmconv<Dm, Hm, true><<<nG12 + C2C, 256, 0, stream>>>(
            Xg, Wb1, b1, (void*)h1, meta,
            W2, Wb2, Hm, Hm, C2A + C2B,    // conv2 tiles [C2A+C2B, nC2)
            nG12);
        k_gemmconv<Hm, Hm, true><<<nG12 + nC3, 256, 0, stream>>>(
            h1, Wb2, b2, (void*)h2, meta,
            W3, Wb3, Hm, Dm, 0,            // conv3 tiles [0, nC3)
            nG12);
        k_gemmconv<Hm, Dm, false><<<nG3, 256, 0, stream>>>(
            h2, Wb3, b3, (void*)eo, meta,
            (const float*)0, (_Float16*)0, 0, 0, 0,
            nG3);

        k_combine<<<NT, 256, 0, stream>>>(eo, pos_of, topw, out);
    } else {
        // ----- serial fallback (shared weight buffer) -----
        _Float16* Xg = (_Float16*)(ws + off); off += sXg;
        _Float16* Wb = (_Float16*)(ws + off); off += sWb2;
        _Float16* h2 = (_Float16*)(ws + off); off += sH;
        _Float16* h1 = (_Float16*)(ws + off);
        float*    eo = (float*)(ws + off);

        k_init<<<1, 64, 0, stream>>>(meta);
        k_gateconv<<<NT / 4, 256, 0, stream>>>(
            x, Wg, bg, meta, list, topw,
            (const float*)0, (_Float16*)0, 0, 0, 0,
            (const float*)0, (_Float16*)0, 0, 0);
        k_plan<<<1, 1, 0, stream>>>(meta);
        k_gather<<<CAPROWS, 256, 0, stream>>>(
            x, meta, list, pos_of, Xg,
            (const float*)0, (_Float16*)0, 0, 0, 0);

        k_convw<<<nC1, 256, 0, stream>>>(W1, Wb, Dm, Hm);
        k_gemmconv<Dm, Hm, true><<<nG12, 256, 0, stream>>>(
            Xg, Wb, b1, (void*)h1, meta,
            (const float*)0, (_Float16*)0, 0, 0, 0, nG12);

        k_convw<<<nC2, 256, 0, stream>>>(W2, Wb, Hm, Hm);
        k_gemmconv<Hm, Hm, true><<<nG12, 256, 0, stream>>>(
            h1, Wb, b2, (void*)h2, meta,
            (const float*)0, (_Float16*)0, 0, 0, 0, nG12);

        k_convw<<<nC3, 256, 0, stream>>>(W3, Wb, Hm, Dm);
        k_gemmconv<Hm, Dm, false><<<nG3, 256, 0, stream>>>(
            h2, Wb, b3, (void*)eo, meta,
            (const float*)0, (_Float16*)0, 0, 0, 0, nG3);

        k_combine<<<NT, 256, 0, stream>>>(eo, pos_of, topw, out);
    }
}